// Round 8
// baseline (176.195 us; speedup 1.0000x reference)
//
#include <hip/hip_runtime.h>
#include <hip/hip_fp8.h>

#define N_NODES 50000
#define N_EDGES 800000
#define IN_C    128
#define HID_C   128
#define OUT_C   64

#define EPB     4096            // edges per scatter block
#define SC_BLOCKS 196           // ceil(N_EDGES / EPB)
#define BSHIFT  6               // bucket = dst >> 6  (64 nodes/bucket)
#define NBUCKET 782             // ceil(50000 / 64)
#define CAP     1536            // max edges per bucket (mean 1024, sigma ~32 -> +16 sigma)
#define G1_BLOCKS 782           // ceil(50000/64)

typedef unsigned int   uint32;
typedef unsigned short ushort16;
typedef unsigned char  uchar8;
typedef __attribute__((ext_vector_type(8))) short short8;
typedef __attribute__((ext_vector_type(4))) float f32x4;

__device__ __forceinline__ ushort16 f2bf(float f) {
    uint32 u = __float_as_uint(f);
    u += 0x7FFFu + ((u >> 16) & 1u);        // RNE
    return (ushort16)(u >> 16);
}
__device__ __forceinline__ float bf_lo(uint32 h) { return __uint_as_float(h << 16); }
__device__ __forceinline__ float bf_hi(uint32 h) { return __uint_as_float(h & 0xFFFF0000u); }

__device__ __forceinline__ ushort16 f2h_bits(float f) {
    union { _Float16 h; ushort16 u; } cv;
    cv.h = (_Float16)f;
    return cv.u;
}
__device__ __forceinline__ float h_bits2f(uint32 bits) {
    union { ushort16 u; _Float16 h; } cv;
    cv.u = (ushort16)bits;
    return (float)cv.h;
}
__device__ __forceinline__ uchar8 f2fp8(float f) {
    __hip_fp8_e4m3 t(f);                    // OCP e4m3fn, RNE-saturating
    return *reinterpret_cast<unsigned char*>(&t);
}
__device__ __forceinline__ float fp82f(uchar8 b) {
    __hip_fp8_e4m3 t;
    *reinterpret_cast<unsigned char*>(&t) = b;
    return (float)t;
}

// ---- W pre-transpose (bf16) + bucket cursor zeroing -------------------------
__global__ __launch_bounds__(256) void prep_w_kernel(const float* __restrict__ W1,
                                                     const float* __restrict__ W2,
                                                     ushort16* __restrict__ W1t,
                                                     ushort16* __restrict__ W2t,
                                                     int* __restrict__ cursorC) {
    if (blockIdx.x == 0)
        for (int j = threadIdx.x; j < NBUCKET; j += 256) cursorC[j] = 0;
    int i = blockIdx.x * 256 + threadIdx.x;
    if (i < 128 * 128) {
        int n = i / 128, k = i % 128;
        W1t[i] = f2bf(W1[k * 128 + n]);
    }
    int j = i - 128 * 128;
    if (j >= 0 && j < 64 * 128) {
        int n = j / 128, k = j % 128;
        W2t[j] = f2bf(W2[k * 64 + n]);
    }
}

// ---- Fused launch: [coarse scatter blocks 0..195] + [gemm1 blocks 196..977] -
__global__ __launch_bounds__(256) void gemm1_scatter_kernel(const float* __restrict__ x,
                                                            const ushort16* __restrict__ W1t,
                                                            uchar8* __restrict__ H1,
                                                            const int* __restrict__ ei,
                                                            const float* __restrict__ ew,
                                                            int* __restrict__ cursorC,
                                                            uint32* __restrict__ key32,
                                                            ushort16* __restrict__ wH) {
    __shared__ char smem[52224];           // union: gemm As+Ws | scatter hist+lbase
    const int tid = threadIdx.x;

    if (blockIdx.x < SC_BLOCKS) {
        int* hist  = (int*)smem;           // [NBUCKET]
        int* lbase = (int*)(smem + 4096);  // [NBUCKET]
        int blk = blockIdx.x;
        for (int i = tid; i < NBUCKET; i += 256) hist[i] = 0;
        __syncthreads();
        int base = blk * EPB;
#pragma unroll
        for (int k = 0; k < EPB / 256; k++) {
            int e = base + tid + k * 256;
            if (e < N_EDGES) atomicAdd(&hist[ei[N_EDGES + e] >> BSHIFT], 1);
        }
        __syncthreads();
        for (int i = tid; i < NBUCKET; i += 256) {
            int n = hist[i];
            lbase[i] = n ? atomicAdd(&cursorC[i], n) : 0;
        }
        __syncthreads();
        for (int i = tid; i < NBUCKET; i += 256) hist[i] = 0;  // reuse: in-block rank
        __syncthreads();
#pragma unroll
        for (int k = 0; k < EPB / 256; k++) {
            int e = base + tid + k * 256;
            if (e < N_EDGES) {
                int dst = ei[N_EDGES + e];
                int src = ei[e];
                float w = ew[e];
                int b = dst >> BSHIFT;
                int r = atomicAdd(&hist[b], 1);
                int pos = lbase[b] + r;
                if (pos < CAP) {
                    int slot = b * CAP + pos;
                    key32[slot] = ((uint32)(dst & 63) << 16) | (uint32)src;
                    wH[slot]    = f2h_bits(w);
                }
            }
        }
        return;
    }

    // ---------------- gemm1 path (MFMA, fp8 epilogue) ------------------------
    typedef ushort16 row136[136];
    row136* As = (row136*)smem;            // [64][136]
    row136* Ws = (row136*)(smem + 64 * 136 * 2);   // [128][136]

    const int wave = tid >> 6;
    const int lane = tid & 63;
    const int quad = lane >> 4;
    const int m    = lane & 15;
    const int blockRow = (blockIdx.x - SC_BLOCKS) * 64;

#pragma unroll
    for (int p = 0; p < 8; p++) {
        int u = tid + 256 * p;
        int row = u / 16, c8 = u % 16;
        uint4 v = ((const uint4*)W1t)[u];
        *((uint4*)&Ws[row][c8 * 8]) = v;
    }
#pragma unroll
    for (int p = 0; p < 8; p++) {
        int u = tid + 256 * p;
        int row = u / 32, c4 = u % 32;
        int gr = blockRow + row; if (gr > N_NODES - 1) gr = N_NODES - 1;
        float4 v = ((const float4*)x)[gr * 32 + c4];
        ushort4 s;
        s.x = f2bf(v.x); s.y = f2bf(v.y); s.z = f2bf(v.z); s.w = f2bf(v.w);
        *((ushort4*)&As[row][c4 * 4]) = s;
    }
    __syncthreads();

    f32x4 acc[8];
#pragma unroll
    for (int nt = 0; nt < 8; nt++) acc[nt] = (f32x4){0.f, 0.f, 0.f, 0.f};

#pragma unroll
    for (int kc = 0; kc < 128; kc += 32) {
        short8 a = *((const short8*)&As[wave * 16 + m][kc + quad * 8]);
#pragma unroll
        for (int nt = 0; nt < 8; nt++) {
            short8 b = *((const short8*)&Ws[nt * 16 + m][kc + quad * 8]);
            acc[nt] = __builtin_amdgcn_mfma_f32_16x16x32_bf16(a, b, acc[nt], 0, 0, 0);
        }
    }

    __syncthreads();
    // fp8 epilogue: regs -> LDS bytes -> coalesced 16B stores (row = 128 B)
    uchar8* c8lds = (uchar8*)&As[0][0];
#pragma unroll
    for (int nt = 0; nt < 8; nt++)
#pragma unroll
        for (int r = 0; r < 4; r++)
            c8lds[(wave * 16 + quad * 4 + r) * 128 + nt * 16 + m] = f2fp8(acc[nt][r]);
    __syncthreads();
#pragma unroll
    for (int p = 0; p < 2; p++) {
        int u = tid + 256 * p;
        int row = u / 8, c16 = u % 8;
        int gr = blockRow + row;
        if (gr < N_NODES)
            ((uint4*)H1)[gr * 8 + c16] = *((const uint4*)&c8lds[row * 128 + c16 * 16]);
    }
}

// ---- Fine sort within each bucket (64 nodes, fixed-stride region b*CAP) -----
// 782 blocks x 256 threads x ~9.5 KB LDS: multi-block/CU for latency hiding.
__global__ __launch_bounds__(256) void csr_fine_kernel(const uint32* __restrict__ key32,
                                                       const ushort16* __restrict__ wH,
                                                       const int* __restrict__ cursorC,
                                                       int* __restrict__ rowStart,
                                                       int* __restrict__ rowEnd,
                                                       uint32* __restrict__ pairs) {
    __shared__ uint32   keys[CAP];
    __shared__ ushort16 ws[CAP];
    __shared__ int hist[64];
    __shared__ int scan[64];
    int b = blockIdx.x, t = threadIdx.x;
    int s = b * CAP;
    int len = cursorC[b];
    if (len > CAP) len = CAP;
    if (t < 64) hist[t] = 0;
    __syncthreads();
    for (int j = t; j < len; j += 256) {
        uint32 kv = key32[s + j];
        keys[j] = kv;
        ws[j]   = wH[s + j];
        atomicAdd(&hist[kv >> 16], 1);   // LDS atomic
    }
    __syncthreads();
    if (t < 64) scan[t] = hist[t];
    __syncthreads();
    for (int off = 1; off < 64; off <<= 1) {
        int a = 0;
        if (t < 64 && t >= off) a = scan[t - off];
        __syncthreads();
        if (t < 64) scan[t] += a;
        __syncthreads();
    }
    if (t < 64) {
        int excl = scan[t] - hist[t];
        hist[t] = excl;
        int node = b * 64 + t;
        if (node < N_NODES) {
            rowStart[node] = s + excl;
            rowEnd[node]   = s + scan[t];
        }
    }
    __syncthreads();
    for (int j = t; j < len; j += 256) {
        uint32 kv = keys[j];
        int r = atomicAdd(&hist[kv >> 16], 1);   // LDS atomic
        pairs[s + r] = (kv & 0xFFFFu) | ((uint32)ws[j] << 16);
    }
}

// ---------------- MFMA GEMM (gemm2): C[M,64] = A[M,128] * W[128,64] ----------
template<int NT, bool ABF16, bool OUTFP8>
__global__ __launch_bounds__(256) void mfma_gemm_kernel(const void* __restrict__ Aptr,
                                                        const ushort16* __restrict__ Wt,
                                                        void* __restrict__ Cout, int M) {
    constexpr int N = NT * 16;
    __shared__ ushort16 As[64][136];
    __shared__ ushort16 Ws[N][136];

    const int tid  = threadIdx.x;
    const int wave = tid >> 6;
    const int lane = tid & 63;
    const int quad = lane >> 4;
    const int m    = lane & 15;
    const int blockRow = blockIdx.x * 64;

#pragma unroll
    for (int p = 0; p < N * 16 / 256; p++) {
        int u = tid + 256 * p;
        int row = u / 16, c8 = u % 16;
        uint4 v = ((const uint4*)Wt)[u];
        *((uint4*)&Ws[row][c8 * 8]) = v;
    }
    if (ABF16) {
#pragma unroll
        for (int p = 0; p < 4; p++) {
            int u = tid + 256 * p;
            int row = u / 16, c8 = u % 16;
            int gr = blockRow + row; if (gr > M - 1) gr = M - 1;
            uint4 v = ((const uint4*)Aptr)[gr * 16 + c8];
            *((uint4*)&As[row][c8 * 8]) = v;
        }
    } else {
#pragma unroll
        for (int p = 0; p < 8; p++) {
            int u = tid + 256 * p;
            int row = u / 32, c4 = u % 32;
            int gr = blockRow + row; if (gr > M - 1) gr = M - 1;
            float4 v = ((const float4*)Aptr)[gr * 32 + c4];
            ushort4 s;
            s.x = f2bf(v.x); s.y = f2bf(v.y); s.z = f2bf(v.z); s.w = f2bf(v.w);
            *((ushort4*)&As[row][c4 * 4]) = s;
        }
    }
    __syncthreads();

    f32x4 acc[NT];
#pragma unroll
    for (int nt = 0; nt < NT; nt++) acc[nt] = (f32x4){0.f, 0.f, 0.f, 0.f};

#pragma unroll
    for (int kc = 0; kc < 128; kc += 32) {
        short8 a = *((const short8*)&As[wave * 16 + m][kc + quad * 8]);
#pragma unroll
        for (int nt = 0; nt < NT; nt++) {
            short8 b = *((const short8*)&Ws[nt * 16 + m][kc + quad * 8]);
            acc[nt] = __builtin_amdgcn_mfma_f32_16x16x32_bf16(a, b, acc[nt], 0, 0, 0);
        }
    }

    __syncthreads();
    if (OUTFP8) {
        uchar8* c8lds = (uchar8*)&As[0][0];
#pragma unroll
        for (int nt = 0; nt < NT; nt++)
#pragma unroll
            for (int r = 0; r < 4; r++)
                c8lds[(wave * 16 + quad * 4 + r) * N + nt * 16 + m] = f2fp8(acc[nt][r]);
        __syncthreads();
#pragma unroll
        for (int p = 0; p < 64 * N / 16 / 256; p++) {
            int u = tid + 256 * p;
            int row = u / (N / 16), c16 = u % (N / 16);
            int gr = blockRow + row;
            if (gr < M)
                ((uint4*)Cout)[gr * (N / 16) + c16] = *((const uint4*)&c8lds[row * N + c16 * 16]);
        }
    } else {
#pragma unroll
        for (int nt = 0; nt < NT; nt++)
#pragma unroll
            for (int r = 0; r < 4; r++)
                As[wave * 16 + quad * 4 + r][nt * 16 + m] = f2bf(acc[nt][r]);
        __syncthreads();
#pragma unroll
        for (int p = 0; p < 64 * N / 8 / 256; p++) {
            int u = tid + 256 * p;
            int row = u / (N / 8), c8 = u % (N / 8);
            int gr = blockRow + row;
            if (gr < M)
                ((uint4*)Cout)[gr * (N / 8) + c8] = *((const uint4*)&As[row][c8 * 8]);
        }
    }
}

// ---- agg1: wave = node, 2 edges per iteration --------------------------------
__global__ __launch_bounds__(256) void agg1_kernel(const uint32* __restrict__ H1,
                                                   const int* __restrict__ rowStart,
                                                   const int* __restrict__ rowEnd,
                                                   const uint32* __restrict__ pairs,
                                                   const float* __restrict__ b1,
                                                   uint32* __restrict__ A1) {
    int node = blockIdx.x * 4 + (threadIdx.x >> 6);
    int lane = threadIdx.x & 63;
    int half = lane >> 5, cl = lane & 31;
    if (node >= N_NODES) return;
    int s = rowStart[node], e = rowEnd[node];
    f32x4 acc = (f32x4){0.f, 0.f, 0.f, 0.f};
    int i = s + half;
    for (; i + 6 < e; i += 8) {          // 4 edges per half, 8 per wave
        uint32 p[4], hw[4];
#pragma unroll
        for (int j = 0; j < 4; j++) p[j] = pairs[i + 2 * j];
#pragma unroll
        for (int j = 0; j < 4; j++) hw[j] = H1[(p[j] & 0xFFFFu) * 32 + cl];
#pragma unroll
        for (int j = 0; j < 4; j++) {
            float w = h_bits2f(p[j] >> 16);
            acc.x += w * fp82f((uchar8)(hw[j] & 0xFF));
            acc.y += w * fp82f((uchar8)((hw[j] >> 8) & 0xFF));
            acc.z += w * fp82f((uchar8)((hw[j] >> 16) & 0xFF));
            acc.w += w * fp82f((uchar8)(hw[j] >> 24));
        }
    }
    for (; i < e; i += 2) {
        uint32 p = pairs[i];
        uint32 hw = H1[(p & 0xFFFFu) * 32 + cl];
        float w = h_bits2f(p >> 16);
        acc.x += w * fp82f((uchar8)(hw & 0xFF));
        acc.y += w * fp82f((uchar8)((hw >> 8) & 0xFF));
        acc.z += w * fp82f((uchar8)((hw >> 16) & 0xFF));
        acc.w += w * fp82f((uchar8)(hw >> 24));
    }
    // combine halves (register-only)
    acc.x += __shfl_xor(acc.x, 32);
    acc.y += __shfl_xor(acc.y, 32);
    acc.z += __shfl_xor(acc.z, 32);
    acc.w += __shfl_xor(acc.w, 32);
    if (half == 0) {
        float4 bb = ((const float4*)b1)[cl];
        float v0 = fmaxf(acc.x + bb.x, 0.f);
        float v1 = fmaxf(acc.y + bb.y, 0.f);
        float v2 = fmaxf(acc.z + bb.z, 0.f);
        float v3 = fmaxf(acc.w + bb.w, 0.f);
        uint2 r;
        r.x = (uint32)f2bf(v0) | ((uint32)f2bf(v1) << 16);
        r.y = (uint32)f2bf(v2) | ((uint32)f2bf(v3) << 16);
        ((uint2*)A1)[node * 32 + cl] = r;
    }
}

// ---- agg2: wave = node, 2 edges per iteration; lane covers 2 fp8 ch ---------
__global__ __launch_bounds__(256) void agg2_kernel(const ushort16* __restrict__ H2,
                                                   const int* __restrict__ rowStart,
                                                   const int* __restrict__ rowEnd,
                                                   const uint32* __restrict__ pairs,
                                                   const float* __restrict__ b2,
                                                   float* __restrict__ out) {
    int node = blockIdx.x * 4 + (threadIdx.x >> 6);
    int lane = threadIdx.x & 63;
    int half = lane >> 5, cl = lane & 31;
    if (node >= N_NODES) return;
    int s = rowStart[node], e = rowEnd[node];
    float2 acc = {0.f, 0.f};
    int i = s + half;
    for (; i + 6 < e; i += 8) {          // 4 edges per half, 8 per wave
        uint32 p[4];
        ushort16 v[4];
#pragma unroll
        for (int j = 0; j < 4; j++) p[j] = pairs[i + 2 * j];
#pragma unroll
        for (int j = 0; j < 4; j++) v[j] = H2[(p[j] & 0xFFFFu) * 32 + cl];
#pragma unroll
        for (int j = 0; j < 4; j++) {
            acc.x += fp82f((uchar8)(v[j] & 0xFF));
            acc.y += fp82f((uchar8)(v[j] >> 8));
        }
    }
    for (; i < e; i += 2) {
        ushort16 v = H2[(pairs[i] & 0xFFFFu) * 32 + cl];
        acc.x += fp82f((uchar8)(v & 0xFF));
        acc.y += fp82f((uchar8)(v >> 8));
    }
    acc.x += __shfl_xor(acc.x, 32);
    acc.y += __shfl_xor(acc.y, 32);
    if (half == 0) {
        float2 bb = ((const float2*)b2)[cl];
        float2 r;
        r.x = acc.x + bb.x;
        r.y = acc.y + bb.y;
        ((float2*)out)[node * 32 + cl] = r;
    }
}

// ---------------- launch -----------------------------------------------------
extern "C" void kernel_launch(void* const* d_in, const int* in_sizes, int n_in,
                              void* d_out, int out_size, void* d_ws, size_t ws_size,
                              hipStream_t stream) {
    const float* x  = (const float*)d_in[0];
    const int*   ei = (const int*)  d_in[1];   // [2, E] int32
    const float* ew = (const float*)d_in[2];
    const float* W1 = (const float*)d_in[3];
    const float* b1 = (const float*)d_in[4];
    const float* W2 = (const float*)d_in[5];
    const float* b2 = (const float*)d_in[6];
    float* out = (float*)d_out;

    // workspace layout (u32 units)
    uint32* H1      = (uint32*)d_ws;                   // 50000*32  (fp8 [N][128])
    uint32* A1      = H1 + (size_t)N_NODES * 32;       // 50000*64  (bf16 [N][128])
    uint32* H2      = A1 + (size_t)N_NODES * 64;       // 50000*16  (fp8 [N][64])
    uint32* pairs   = H2 + (size_t)N_NODES * 16;       // NBUCKET*CAP (src u16 | f16 w)
    uint32* key32   = pairs + (size_t)NBUCKET * CAP;   // NBUCKET*CAP (fine<<16 | src)
    ushort16* wH    = (ushort16*)(key32 + (size_t)NBUCKET * CAP);  // NBUCKET*CAP u16
    ushort16* W1t   = wH + (size_t)NBUCKET * CAP + (((size_t)NBUCKET * CAP) & 1);
    ushort16* W2t   = W1t + 128 * 128;                 // 64*128 bf16 transposed
    int* cursorC    = (int*)(W2t + 64 * 128);          // NBUCKET
    int* rowStart   = cursorC + ((NBUCKET + 1) & ~1);  // 50000
    int* rowEnd     = rowStart + N_NODES;              // 50000

    const int nodeBlocks = (N_NODES + 3) / 4;       // 12500

    // W transposes (bf16) + zero bucket cursors
    prep_w_kernel<<<96, 256, 0, stream>>>(W1, W2, W1t, W2t, cursorC);

    // fused: coarse scatter (blocks 0..195) || H1(fp8) = x @ W1 (blocks 196..977)
    gemm1_scatter_kernel<<<SC_BLOCKS + G1_BLOCKS, 256, 0, stream>>>(
        x, W1t, (uchar8*)H1, ei, ew, cursorC, key32, wH);

    // fine sort to node granularity (782 blocks, 64-node buckets)
    csr_fine_kernel<<<NBUCKET, 256, 0, stream>>>(key32, wH, cursorC, rowStart, rowEnd, pairs);

    // A1(bf16) = relu(segment_sum(w * H1fp8[src]) + b1)   [wave-per-node, 2 edges/iter]
    agg1_kernel<<<nodeBlocks, 256, 0, stream>>>(H1, rowStart, rowEnd, pairs, b1, A1);

    // H2(fp8) = A1 @ W2   [MFMA, bf16 A, fp8 out]
    mfma_gemm_kernel<4, true, true><<<G1_BLOCKS, 256, 0, stream>>>(A1, W2t, H2, N_NODES);

    // out = segment_sum(H2[src]) + b2   [wave-per-node, 2 edges/iter]
    agg2_kernel<<<nodeBlocks, 256, 0, stream>>>((const ushort16*)H2, rowStart, rowEnd, pairs, b2, out);
}

// Round 9
// 166.707 us; speedup vs baseline: 1.0569x; 1.0569x over previous
//
#include <hip/hip_runtime.h>
#include <hip/hip_fp8.h>

#define N_NODES 50000
#define N_EDGES 800000
#define IN_C    128
#define HID_C   128
#define OUT_C   64

#define EPB     4096            // edges per scatter block
#define SC_BLOCKS 196           // ceil(N_EDGES / EPB)
#define NBUCKET 196             // ceil(N_NODES / 256)  (round-7 verified shape)
#define CAP     6144            // max edges per coarse bucket (mean 4096, +32 sigma)
#define G1_BLOCKS 782           // ceil(50000/64)

typedef unsigned int       uint32;
typedef unsigned short     ushort16;
typedef unsigned char      uchar8;
typedef unsigned long long u64;
typedef __attribute__((ext_vector_type(8))) short short8;
typedef __attribute__((ext_vector_type(4))) float f32x4;

__device__ __forceinline__ ushort16 f2bf(float f) {
    uint32 u = __float_as_uint(f);
    u += 0x7FFFu + ((u >> 16) & 1u);        // RNE
    return (ushort16)(u >> 16);
}
__device__ __forceinline__ ushort16 f2h_bits(float f) {
    union { _Float16 h; ushort16 u; } cv;
    cv.h = (_Float16)f;
    return cv.u;
}
__device__ __forceinline__ float h_bits2f(uint32 bits) {
    union { ushort16 u; _Float16 h; } cv;
    cv.u = (ushort16)bits;
    return (float)cv.h;
}
__device__ __forceinline__ uchar8 f2fp8(float f) {
    __hip_fp8_e4m3 t(f);                    // OCP e4m3fn, RNE-saturating
    return *reinterpret_cast<unsigned char*>(&t);
}
__device__ __forceinline__ float fp82f(uchar8 b) {
    __hip_fp8_e4m3 t;
    *reinterpret_cast<unsigned char*>(&t) = b;
    return (float)t;
}
// accumulate 4 fp8 channels from a u32, weighted / unweighted
__device__ __forceinline__ void fp8x4_wacc(uint32 v, float w, f32x4& a) {
    a.x += w * fp82f((uchar8)(v & 0xFF));
    a.y += w * fp82f((uchar8)((v >> 8) & 0xFF));
    a.z += w * fp82f((uchar8)((v >> 16) & 0xFF));
    a.w += w * fp82f((uchar8)(v >> 24));
}
__device__ __forceinline__ void fp8x4_acc(uint32 v, f32x4& a) {
    a.x += fp82f((uchar8)(v & 0xFF));
    a.y += fp82f((uchar8)((v >> 8) & 0xFF));
    a.z += fp82f((uchar8)((v >> 16) & 0xFF));
    a.w += fp82f((uchar8)(v >> 24));
}

// ---- W pre-transpose (bf16) + coarse-bucket cursor zeroing ------------------
__global__ __launch_bounds__(256) void prep_w_kernel(const float* __restrict__ W1,
                                                     const float* __restrict__ W2,
                                                     ushort16* __restrict__ W1t,
                                                     ushort16* __restrict__ W2t,
                                                     int* __restrict__ cursorC) {
    if (blockIdx.x == 0 && threadIdx.x < NBUCKET) cursorC[threadIdx.x] = 0;
    int i = blockIdx.x * 256 + threadIdx.x;
    if (i < 128 * 128) {
        int n = i / 128, k = i % 128;
        W1t[i] = f2bf(W1[k * 128 + n]);
    }
    int j = i - 128 * 128;
    if (j >= 0 && j < 64 * 128) {
        int n = j / 128, k = j % 128;
        W2t[j] = f2bf(W2[k * 64 + n]);
    }
}

// ---- Fused launch: [coarse scatter blocks 0..195] + [gemm1 blocks 196..977] -
// scatter: LDS hist -> one global atomic per (block,bucket) -> ONE u64 staged
//          store per edge (w<<32 | fine<<16 | src) into bucket region b*CAP.
// gemm1:   H1(fp8 e4m3) = x @ W1 via MFMA, fp8 epilogue.
__global__ __launch_bounds__(256) void gemm1_scatter_kernel(const float* __restrict__ x,
                                                            const ushort16* __restrict__ W1t,
                                                            uchar8* __restrict__ H1,
                                                            const int* __restrict__ ei,
                                                            const float* __restrict__ ew,
                                                            int* __restrict__ cursorC,
                                                            u64* __restrict__ ebuf) {
    __shared__ char smem[52224];           // union: gemm As+Ws | scatter hist+lbase
    const int tid = threadIdx.x;

    if (blockIdx.x < SC_BLOCKS) {
        int* hist  = (int*)smem;           // [256]
        int* lbase = (int*)(smem + 1024);  // [256]
        int blk = blockIdx.x;
        hist[tid] = 0;
        __syncthreads();
        int base = blk * EPB;
#pragma unroll
        for (int k = 0; k < EPB / 256; k++) {
            int e = base + tid + k * 256;
            if (e < N_EDGES) atomicAdd(&hist[ei[N_EDGES + e] >> 8], 1);
        }
        __syncthreads();
        int n = hist[tid];
        lbase[tid] = n ? atomicAdd(&cursorC[tid], n) : 0;
        __syncthreads();
        hist[tid] = 0;                     // reuse as in-block rank cursor
        __syncthreads();
#pragma unroll
        for (int k = 0; k < EPB / 256; k++) {
            int e = base + tid + k * 256;
            if (e < N_EDGES) {
                int dst = ei[N_EDGES + e];
                int src = ei[e];
                float w = ew[e];
                int b = dst >> 8;
                int r = atomicAdd(&hist[b], 1);
                int pos = lbase[b] + r;
                if (pos < CAP)
                    ebuf[(size_t)b * CAP + pos] =
                        ((u64)f2h_bits(w) << 32) | ((uint32)(dst & 255) << 16) | (uint32)src;
            }
        }
        return;
    }

    // ---------------- gemm1 path (MFMA, fp8 epilogue) ------------------------
    typedef ushort16 row136[136];
    row136* As = (row136*)smem;            // [64][136]
    row136* Ws = (row136*)(smem + 64 * 136 * 2);   // [128][136]

    const int wave = tid >> 6;
    const int lane = tid & 63;
    const int quad = lane >> 4;
    const int m    = lane & 15;
    const int blockRow = (blockIdx.x - SC_BLOCKS) * 64;

#pragma unroll
    for (int p = 0; p < 8; p++) {
        int u = tid + 256 * p;
        int row = u / 16, c8 = u % 16;
        uint4 v = ((const uint4*)W1t)[u];
        *((uint4*)&Ws[row][c8 * 8]) = v;
    }
#pragma unroll
    for (int p = 0; p < 8; p++) {
        int u = tid + 256 * p;
        int row = u / 32, c4 = u % 32;
        int gr = blockRow + row; if (gr > N_NODES - 1) gr = N_NODES - 1;
        float4 v = ((const float4*)x)[gr * 32 + c4];
        ushort4 s;
        s.x = f2bf(v.x); s.y = f2bf(v.y); s.z = f2bf(v.z); s.w = f2bf(v.w);
        *((ushort4*)&As[row][c4 * 4]) = s;
    }
    __syncthreads();

    f32x4 acc[8];
#pragma unroll
    for (int nt = 0; nt < 8; nt++) acc[nt] = (f32x4){0.f, 0.f, 0.f, 0.f};

#pragma unroll
    for (int kc = 0; kc < 128; kc += 32) {
        short8 a = *((const short8*)&As[wave * 16 + m][kc + quad * 8]);
#pragma unroll
        for (int nt = 0; nt < 8; nt++) {
            short8 b = *((const short8*)&Ws[nt * 16 + m][kc + quad * 8]);
            acc[nt] = __builtin_amdgcn_mfma_f32_16x16x32_bf16(a, b, acc[nt], 0, 0, 0);
        }
    }

    __syncthreads();
    // fp8 epilogue: regs -> LDS bytes -> coalesced 16B stores (row = 128 B)
    uchar8* c8lds = (uchar8*)&As[0][0];
#pragma unroll
    for (int nt = 0; nt < 8; nt++)
#pragma unroll
        for (int r = 0; r < 4; r++)
            c8lds[(wave * 16 + quad * 4 + r) * 128 + nt * 16 + m] = f2fp8(acc[nt][r]);
    __syncthreads();
#pragma unroll
    for (int p = 0; p < 2; p++) {
        int u = tid + 256 * p;
        int row = u / 8, c16 = u % 8;
        int gr = blockRow + row;
        if (gr < N_NODES)
            ((uint4*)H1)[gr * 8 + c16] = *((const uint4*)&c8lds[row * 128 + c16 * 16]);
    }
}

// ---- Fine sort within each coarse bucket (round-7 verified shape) -----------
__global__ __launch_bounds__(1024) void csr_fine_kernel(const u64* __restrict__ ebuf,
                                                        const int* __restrict__ cursorC,
                                                        int* __restrict__ rowStart,
                                                        int* __restrict__ rowEnd,
                                                        uint32* __restrict__ pairs) {
    __shared__ uint32   keys[CAP];
    __shared__ ushort16 ws[CAP];
    __shared__ int hist[256];
    __shared__ int scan[256];
    int b = blockIdx.x, t = threadIdx.x;
    int s = b * CAP;
    int len = cursorC[b];
    if (len > CAP) len = CAP;
    if (t < 256) hist[t] = 0;
    __syncthreads();
    for (int j = t; j < len; j += 1024) {
        u64 kv = ebuf[s + j];
        uint32 lo = (uint32)kv;
        keys[j] = lo;
        ws[j]   = (ushort16)(kv >> 32);
        atomicAdd(&hist[lo >> 16], 1);   // LDS atomic
    }
    __syncthreads();
    if (t < 256) scan[t] = hist[t];
    __syncthreads();
    for (int off = 1; off < 256; off <<= 1) {
        int a = 0;
        if (t < 256 && t >= off) a = scan[t - off];
        __syncthreads();
        if (t < 256) scan[t] += a;
        __syncthreads();
    }
    if (t < 256) {
        int excl = scan[t] - hist[t];
        hist[t] = excl;
        int node = b * 256 + t;
        if (node < N_NODES) {
            rowStart[node] = s + excl;
            rowEnd[node]   = s + scan[t];
        }
    }
    __syncthreads();
    for (int j = t; j < len; j += 1024) {
        uint32 kv = keys[j];
        int r = atomicAdd(&hist[kv >> 16], 1);   // LDS atomic
        pairs[s + r] = (kv & 0xFFFFu) | ((uint32)ws[j] << 16);
    }
}

// ---------------- MFMA GEMM (gemm2): C[M,64] = A[M,128] * W[128,64] ----------
template<int NT, bool ABF16, bool OUTFP8>
__global__ __launch_bounds__(256) void mfma_gemm_kernel(const void* __restrict__ Aptr,
                                                        const ushort16* __restrict__ Wt,
                                                        void* __restrict__ Cout, int M) {
    constexpr int N = NT * 16;
    __shared__ ushort16 As[64][136];
    __shared__ ushort16 Ws[N][136];

    const int tid  = threadIdx.x;
    const int wave = tid >> 6;
    const int lane = tid & 63;
    const int quad = lane >> 4;
    const int m    = lane & 15;
    const int blockRow = blockIdx.x * 64;

#pragma unroll
    for (int p = 0; p < N * 16 / 256; p++) {
        int u = tid + 256 * p;
        int row = u / 16, c8 = u % 16;
        uint4 v = ((const uint4*)Wt)[u];
        *((uint4*)&Ws[row][c8 * 8]) = v;
    }
    if (ABF16) {
#pragma unroll
        for (int p = 0; p < 4; p++) {
            int u = tid + 256 * p;
            int row = u / 16, c8 = u % 16;
            int gr = blockRow + row; if (gr > M - 1) gr = M - 1;
            uint4 v = ((const uint4*)Aptr)[gr * 16 + c8];
            *((uint4*)&As[row][c8 * 8]) = v;
        }
    } else {
#pragma unroll
        for (int p = 0; p < 8; p++) {
            int u = tid + 256 * p;
            int row = u / 32, c4 = u % 32;
            int gr = blockRow + row; if (gr > M - 1) gr = M - 1;
            float4 v = ((const float4*)Aptr)[gr * 32 + c4];
            ushort4 s;
            s.x = f2bf(v.x); s.y = f2bf(v.y); s.z = f2bf(v.z); s.w = f2bf(v.w);
            *((ushort4*)&As[row][c4 * 4]) = s;
        }
    }
    __syncthreads();

    f32x4 acc[NT];
#pragma unroll
    for (int nt = 0; nt < NT; nt++) acc[nt] = (f32x4){0.f, 0.f, 0.f, 0.f};

#pragma unroll
    for (int kc = 0; kc < 128; kc += 32) {
        short8 a = *((const short8*)&As[wave * 16 + m][kc + quad * 8]);
#pragma unroll
        for (int nt = 0; nt < NT; nt++) {
            short8 b = *((const short8*)&Ws[nt * 16 + m][kc + quad * 8]);
            acc[nt] = __builtin_amdgcn_mfma_f32_16x16x32_bf16(a, b, acc[nt], 0, 0, 0);
        }
    }

    __syncthreads();
    if (OUTFP8) {
        uchar8* c8lds = (uchar8*)&As[0][0];
#pragma unroll
        for (int nt = 0; nt < NT; nt++)
#pragma unroll
            for (int r = 0; r < 4; r++)
                c8lds[(wave * 16 + quad * 4 + r) * N + nt * 16 + m] = f2fp8(acc[nt][r]);
        __syncthreads();
#pragma unroll
        for (int p = 0; p < 64 * N / 16 / 256; p++) {
            int u = tid + 256 * p;
            int row = u / (N / 16), c16 = u % (N / 16);
            int gr = blockRow + row;
            if (gr < M)
                ((uint4*)Cout)[gr * (N / 16) + c16] = *((const uint4*)&c8lds[row * N + c16 * 16]);
        }
    } else {
#pragma unroll
        for (int nt = 0; nt < NT; nt++)
#pragma unroll
            for (int r = 0; r < 4; r++)
                As[wave * 16 + quad * 4 + r][nt * 16 + m] = f2bf(acc[nt][r]);
        __syncthreads();
#pragma unroll
        for (int p = 0; p < 64 * N / 8 / 256; p++) {
            int u = tid + 256 * p;
            int row = u / (N / 8), c8 = u % (N / 8);
            int gr = blockRow + row;
            if (gr < M)
                ((uint4*)Cout)[gr * (N / 8) + c8] = *((const uint4*)&As[row][c8 * 8]);
        }
    }
}

// ---- agg1: wave = node, 4 edges in flight (quarters), 8B/lane gather --------
// quarter q owns edge slots i%4==q; 16 lanes x uint2 cover the 128B H1 row.
__global__ __launch_bounds__(256) void agg1_kernel(const uint2* __restrict__ H1,
                                                   const int* __restrict__ rowStart,
                                                   const int* __restrict__ rowEnd,
                                                   const uint32* __restrict__ pairs,
                                                   const float* __restrict__ b1,
                                                   uint4* __restrict__ A1) {
    int node = blockIdx.x * 4 + (threadIdx.x >> 6);
    int lane = threadIdx.x & 63;
    int q = lane >> 4, cl = lane & 15;
    if (node >= N_NODES) return;
    int s = rowStart[node], e = rowEnd[node];
    f32x4 aA = (f32x4){0.f, 0.f, 0.f, 0.f};
    f32x4 aB = (f32x4){0.f, 0.f, 0.f, 0.f};
    int i = s + q;
    for (; i + 4 < e; i += 8) {          // 2 edges per quarter, 8 per wave
        uint32 p0 = pairs[i], p1 = pairs[i + 4];
        uint2 h0 = H1[(p0 & 0xFFFFu) * 16 + cl];
        uint2 h1 = H1[(p1 & 0xFFFFu) * 16 + cl];
        float w0 = h_bits2f(p0 >> 16), w1 = h_bits2f(p1 >> 16);
        fp8x4_wacc(h0.x, w0, aA); fp8x4_wacc(h0.y, w0, aB);
        fp8x4_wacc(h1.x, w1, aA); fp8x4_wacc(h1.y, w1, aB);
    }
    for (; i < e; i += 4) {
        uint32 p = pairs[i];
        uint2 h = H1[(p & 0xFFFFu) * 16 + cl];
        float w = h_bits2f(p >> 16);
        fp8x4_wacc(h.x, w, aA); fp8x4_wacc(h.y, w, aB);
    }
    // combine quarters (register-only butterfly over lanes 16, 32)
#pragma unroll
    for (int d = 16; d <= 32; d <<= 1) {
        aA.x += __shfl_xor(aA.x, d); aA.y += __shfl_xor(aA.y, d);
        aA.z += __shfl_xor(aA.z, d); aA.w += __shfl_xor(aA.w, d);
        aB.x += __shfl_xor(aB.x, d); aB.y += __shfl_xor(aB.y, d);
        aB.z += __shfl_xor(aB.z, d); aB.w += __shfl_xor(aB.w, d);
    }
    if (q == 0) {
        float4 b0 = ((const float4*)b1)[cl * 2];
        float4 b4 = ((const float4*)b1)[cl * 2 + 1];
        uint4 r;
        r.x = (uint32)f2bf(fmaxf(aA.x + b0.x, 0.f)) | ((uint32)f2bf(fmaxf(aA.y + b0.y, 0.f)) << 16);
        r.y = (uint32)f2bf(fmaxf(aA.z + b0.z, 0.f)) | ((uint32)f2bf(fmaxf(aA.w + b0.w, 0.f)) << 16);
        r.z = (uint32)f2bf(fmaxf(aB.x + b4.x, 0.f)) | ((uint32)f2bf(fmaxf(aB.y + b4.y, 0.f)) << 16);
        r.w = (uint32)f2bf(fmaxf(aB.z + b4.z, 0.f)) | ((uint32)f2bf(fmaxf(aB.w + b4.w, 0.f)) << 16);
        A1[node * 16 + cl] = r;
    }
}

// ---- agg2: wave = node, 4 edges in flight (quarters), 4B/lane gather --------
// 16 lanes x uint32 cover the 64B H2 row (4 fp8 channels per lane).
__global__ __launch_bounds__(256) void agg2_kernel(const uint32* __restrict__ H2,
                                                   const int* __restrict__ rowStart,
                                                   const int* __restrict__ rowEnd,
                                                   const uint32* __restrict__ pairs,
                                                   const float* __restrict__ b2,
                                                   float4* __restrict__ out) {
    int node = blockIdx.x * 4 + (threadIdx.x >> 6);
    int lane = threadIdx.x & 63;
    int q = lane >> 4, cl = lane & 15;
    if (node >= N_NODES) return;
    int s = rowStart[node], e = rowEnd[node];
    f32x4 acc = (f32x4){0.f, 0.f, 0.f, 0.f};
    int i = s + q;
    for (; i + 4 < e; i += 8) {          // 2 edges per quarter, 8 per wave
        uint32 p0 = pairs[i], p1 = pairs[i + 4];
        uint32 v0 = H2[(p0 & 0xFFFFu) * 16 + cl];
        uint32 v1 = H2[(p1 & 0xFFFFu) * 16 + cl];
        fp8x4_acc(v0, acc);
        fp8x4_acc(v1, acc);
    }
    for (; i < e; i += 4) {
        uint32 v = H2[(pairs[i] & 0xFFFFu) * 16 + cl];
        fp8x4_acc(v, acc);
    }
#pragma unroll
    for (int d = 16; d <= 32; d <<= 1) {
        acc.x += __shfl_xor(acc.x, d); acc.y += __shfl_xor(acc.y, d);
        acc.z += __shfl_xor(acc.z, d); acc.w += __shfl_xor(acc.w, d);
    }
    if (q == 0) {
        float4 bb = ((const float4*)b2)[cl];
        float4 r;
        r.x = acc.x + bb.x; r.y = acc.y + bb.y;
        r.z = acc.z + bb.z; r.w = acc.w + bb.w;
        out[node * 16 + cl] = r;
    }
}

// ---------------- launch -----------------------------------------------------
extern "C" void kernel_launch(void* const* d_in, const int* in_sizes, int n_in,
                              void* d_out, int out_size, void* d_ws, size_t ws_size,
                              hipStream_t stream) {
    const float* x  = (const float*)d_in[0];
    const int*   ei = (const int*)  d_in[1];   // [2, E] int32
    const float* ew = (const float*)d_in[2];
    const float* W1 = (const float*)d_in[3];
    const float* b1 = (const float*)d_in[4];
    const float* W2 = (const float*)d_in[5];
    const float* b2 = (const float*)d_in[6];
    float* out = (float*)d_out;

    // workspace layout (u32 units)
    uint32* H1      = (uint32*)d_ws;                   // 50000*32  (fp8 [N][128])
    uint32* A1      = H1 + (size_t)N_NODES * 32;       // 50000*64  (bf16 [N][128])
    uint32* H2      = A1 + (size_t)N_NODES * 64;       // 50000*16  (fp8 [N][64])
    uint32* pairs   = H2 + (size_t)N_NODES * 16;       // NBUCKET*CAP (src u16 | f16 w)
    u64* ebuf       = (u64*)(pairs + (size_t)NBUCKET * CAP);  // NBUCKET*CAP u64 staged
    ushort16* W1t   = (ushort16*)(ebuf + (size_t)NBUCKET * CAP);
    ushort16* W2t   = W1t + 128 * 128;                 // 64*128 bf16 transposed
    int* cursorC    = (int*)(W2t + 64 * 128);          // NBUCKET
    int* rowStart   = cursorC + ((NBUCKET + 1) & ~1);  // 50000
    int* rowEnd     = rowStart + N_NODES;              // 50000

    const int nodeBlocks = (N_NODES + 3) / 4;       // 12500

    // W transposes (bf16) + zero coarse cursors
    prep_w_kernel<<<96, 256, 0, stream>>>(W1, W2, W1t, W2t, cursorC);

    // fused: coarse scatter (blocks 0..195) || H1(fp8) = x @ W1 (blocks 196..977)
    gemm1_scatter_kernel<<<SC_BLOCKS + G1_BLOCKS, 256, 0, stream>>>(
        x, W1t, (uchar8*)H1, ei, ew, cursorC, ebuf);

    // fine sort to node granularity within each bucket region
    csr_fine_kernel<<<NBUCKET, 1024, 0, stream>>>(ebuf, cursorC, rowStart, rowEnd, pairs);

    // A1(bf16) = relu(segment_sum(w * H1fp8[src]) + b1)   [wave-per-node, 4 edges in flight]
    agg1_kernel<<<nodeBlocks, 256, 0, stream>>>((const uint2*)H1, rowStart, rowEnd, pairs, b1, (uint4*)A1);

    // H2(fp8) = A1 @ W2   [MFMA, bf16 A, fp8 out]
    mfma_gemm_kernel<4, true, true><<<G1_BLOCKS, 256, 0, stream>>>(A1, W2t, H2, N_NODES);

    // out = segment_sum(H2[src]) + b2   [wave-per-node, 4 edges in flight]
    agg2_kernel<<<nodeBlocks, 256, 0, stream>>>((const uint32*)H2, rowStart, rowEnd, pairs, b2, (float4*)out);
}

// Round 10
// 164.107 us; speedup vs baseline: 1.0737x; 1.0158x over previous
//
#include <hip/hip_runtime.h>
#include <hip/hip_fp8.h>

#define N_NODES 50000
#define N_EDGES 800000
#define IN_C    128
#define HID_C   128
#define OUT_C   64

#define EPB     4096            // edges per scatter block
#define SC_BLOCKS 196           // ceil(N_EDGES / EPB)
#define NBUCKET 196             // ceil(N_NODES / 256)
#define CAP     6144            // max edges per coarse bucket (mean 4096, +32 sigma)
#define G1_BLOCKS 782           // ceil(50000/64)

typedef unsigned int       uint32;
typedef unsigned short     ushort16;
typedef unsigned char      uchar8;
typedef unsigned long long u64;
typedef __attribute__((ext_vector_type(8))) short short8;
typedef __attribute__((ext_vector_type(4))) float f32x4;

__device__ __forceinline__ ushort16 f2bf(float f) {
    uint32 u = __float_as_uint(f);
    u += 0x7FFFu + ((u >> 16) & 1u);        // RNE
    return (ushort16)(u >> 16);
}
__device__ __forceinline__ ushort16 f2h_bits(float f) {
    union { _Float16 h; ushort16 u; } cv;
    cv.h = (_Float16)f;
    return cv.u;
}
__device__ __forceinline__ float h_bits2f(uint32 bits) {
    union { ushort16 u; _Float16 h; } cv;
    cv.u = (ushort16)bits;
    return (float)cv.h;
}
__device__ __forceinline__ uchar8 f2fp8(float f) {
    __hip_fp8_e4m3 t(f);                    // OCP e4m3fn, RNE-saturating
    return *reinterpret_cast<unsigned char*>(&t);
}
__device__ __forceinline__ float fp82f(uchar8 b) {
    __hip_fp8_e4m3 t;
    *reinterpret_cast<unsigned char*>(&t) = b;
    return (float)t;
}
__device__ __forceinline__ void fp8x4_wacc(uint32 v, float w, f32x4& a) {
    a.x += w * fp82f((uchar8)(v & 0xFF));
    a.y += w * fp82f((uchar8)((v >> 8) & 0xFF));
    a.z += w * fp82f((uchar8)((v >> 16) & 0xFF));
    a.w += w * fp82f((uchar8)(v >> 24));
}
__device__ __forceinline__ void fp8x4_acc(uint32 v, f32x4& a) {
    a.x += fp82f((uchar8)(v & 0xFF));
    a.y += fp82f((uchar8)((v >> 8) & 0xFF));
    a.z += fp82f((uchar8)((v >> 16) & 0xFF));
    a.w += fp82f((uchar8)(v >> 24));
}
__device__ __forceinline__ void bfly4(f32x4& a, int d) {
    a.x += __shfl_xor(a.x, d); a.y += __shfl_xor(a.y, d);
    a.z += __shfl_xor(a.z, d); a.w += __shfl_xor(a.w, d);
}
__device__ __forceinline__ uint32 packbf(float a, float b) {
    return (uint32)f2bf(a) | ((uint32)f2bf(b) << 16);
}

// ---- W pre-transpose (bf16) + coarse-bucket cursor zeroing ------------------
__global__ __launch_bounds__(256) void prep_w_kernel(const float* __restrict__ W1,
                                                     const float* __restrict__ W2,
                                                     ushort16* __restrict__ W1t,
                                                     ushort16* __restrict__ W2t,
                                                     int* __restrict__ cursorC) {
    if (blockIdx.x == 0 && threadIdx.x < NBUCKET) cursorC[threadIdx.x] = 0;
    int i = blockIdx.x * 256 + threadIdx.x;
    if (i < 128 * 128) {
        int n = i / 128, k = i % 128;
        W1t[i] = f2bf(W1[k * 128 + n]);
    }
    int j = i - 128 * 128;
    if (j >= 0 && j < 64 * 128) {
        int n = j / 128, k = j % 128;
        W2t[j] = f2bf(W2[k * 64 + n]);
    }
}

// ---- Fused launch: [coarse scatter blocks 0..195] + [gemm1 blocks 196..977] -
// scatter: single edge read pass (regs cache packed edges across the two
//          LDS-atomic passes) -> one u64 staged store per edge.
// gemm1:   H1(fp8 e4m3) = x @ W1 via MFMA, fp8 epilogue.
__global__ __launch_bounds__(256) void gemm1_scatter_kernel(const float* __restrict__ x,
                                                            const ushort16* __restrict__ W1t,
                                                            uchar8* __restrict__ H1,
                                                            const int* __restrict__ ei,
                                                            const float* __restrict__ ew,
                                                            int* __restrict__ cursorC,
                                                            u64* __restrict__ ebuf) {
    __shared__ char smem[52224];           // union: gemm As+Ws | scatter hist+lbase
    const int tid = threadIdx.x;

    if (blockIdx.x < SC_BLOCKS) {
        int* hist  = (int*)smem;           // [256]
        int* lbase = (int*)(smem + 1024);  // [256]
        int blk = blockIdx.x;
        hist[tid] = 0;
        __syncthreads();
        int base = blk * EPB;
        int    bv[EPB / 256];
        uint32 pkv[EPB / 256];
        ushort16 wv[EPB / 256];
#pragma unroll
        for (int k = 0; k < EPB / 256; k++) {
            int e = base + tid + k * 256;
            if (e < N_EDGES) {
                int dst = ei[N_EDGES + e];
                int src = ei[e];
                float w = ew[e];
                bv[k]  = dst >> 8;
                pkv[k] = ((uint32)(dst & 255) << 16) | (uint32)src;
                wv[k]  = f2h_bits(w);
                atomicAdd(&hist[bv[k]], 1);
            } else bv[k] = -1;
        }
        __syncthreads();
        int n = hist[tid];
        lbase[tid] = n ? atomicAdd(&cursorC[tid], n) : 0;
        __syncthreads();
        hist[tid] = 0;                     // reuse as in-block rank cursor
        __syncthreads();
#pragma unroll
        for (int k = 0; k < EPB / 256; k++) {
            if (bv[k] >= 0) {
                int b = bv[k];
                int r = atomicAdd(&hist[b], 1);
                int pos = lbase[b] + r;
                if (pos < CAP)
                    ebuf[(size_t)b * CAP + pos] = ((u64)wv[k] << 32) | pkv[k];
            }
        }
        return;
    }

    // ---------------- gemm1 path (MFMA, fp8 epilogue) ------------------------
    typedef ushort16 row136[136];
    row136* As = (row136*)smem;            // [64][136]
    row136* Ws = (row136*)(smem + 64 * 136 * 2);   // [128][136]

    const int wave = tid >> 6;
    const int lane = tid & 63;
    const int quad = lane >> 4;
    const int m    = lane & 15;
    const int blockRow = (blockIdx.x - SC_BLOCKS) * 64;

#pragma unroll
    for (int p = 0; p < 8; p++) {
        int u = tid + 256 * p;
        int row = u / 16, c8 = u % 16;
        uint4 v = ((const uint4*)W1t)[u];
        *((uint4*)&Ws[row][c8 * 8]) = v;
    }
#pragma unroll
    for (int p = 0; p < 8; p++) {
        int u = tid + 256 * p;
        int row = u / 32, c4 = u % 32;
        int gr = blockRow + row; if (gr > N_NODES - 1) gr = N_NODES - 1;
        float4 v = ((const float4*)x)[gr * 32 + c4];
        ushort4 s;
        s.x = f2bf(v.x); s.y = f2bf(v.y); s.z = f2bf(v.z); s.w = f2bf(v.w);
        *((ushort4*)&As[row][c4 * 4]) = s;
    }
    __syncthreads();

    f32x4 acc[8];
#pragma unroll
    for (int nt = 0; nt < 8; nt++) acc[nt] = (f32x4){0.f, 0.f, 0.f, 0.f};

#pragma unroll
    for (int kc = 0; kc < 128; kc += 32) {
        short8 a = *((const short8*)&As[wave * 16 + m][kc + quad * 8]);
#pragma unroll
        for (int nt = 0; nt < 8; nt++) {
            short8 b = *((const short8*)&Ws[nt * 16 + m][kc + quad * 8]);
            acc[nt] = __builtin_amdgcn_mfma_f32_16x16x32_bf16(a, b, acc[nt], 0, 0, 0);
        }
    }

    __syncthreads();
    // fp8 epilogue: regs -> LDS bytes -> coalesced 16B stores (row = 128 B)
    uchar8* c8lds = (uchar8*)&As[0][0];
#pragma unroll
    for (int nt = 0; nt < 8; nt++)
#pragma unroll
        for (int r = 0; r < 4; r++)
            c8lds[(wave * 16 + quad * 4 + r) * 128 + nt * 16 + m] = f2fp8(acc[nt][r]);
    __syncthreads();
#pragma unroll
    for (int p = 0; p < 2; p++) {
        int u = tid + 256 * p;
        int row = u / 8, c16 = u % 8;
        int gr = blockRow + row;
        if (gr < N_NODES)
            ((uint4*)H1)[gr * 8 + c16] = *((const uint4*)&c8lds[row * 128 + c16 * 16]);
    }
}

// ---- Fine sort within each coarse bucket (fixed-stride region b*CAP) --------
__global__ __launch_bounds__(1024) void csr_fine_kernel(const u64* __restrict__ ebuf,
                                                        const int* __restrict__ cursorC,
                                                        int* __restrict__ rowStart,
                                                        int* __restrict__ rowEnd,
                                                        uint32* __restrict__ pairs) {
    __shared__ uint32   keys[CAP];
    __shared__ ushort16 ws[CAP];
    __shared__ int hist[256];
    __shared__ int scan[256];
    int b = blockIdx.x, t = threadIdx.x;
    int s = b * CAP;
    int len = cursorC[b];
    if (len > CAP) len = CAP;
    if (t < 256) hist[t] = 0;
    __syncthreads();
    for (int j = t; j < len; j += 1024) {
        u64 kv = ebuf[s + j];
        uint32 lo = (uint32)kv;
        keys[j] = lo;
        ws[j]   = (ushort16)(kv >> 32);
        atomicAdd(&hist[lo >> 16], 1);   // LDS atomic
    }
    __syncthreads();
    if (t < 256) scan[t] = hist[t];
    __syncthreads();
    for (int off = 1; off < 256; off <<= 1) {
        int a = 0;
        if (t < 256 && t >= off) a = scan[t - off];
        __syncthreads();
        if (t < 256) scan[t] += a;
        __syncthreads();
    }
    if (t < 256) {
        int excl = scan[t] - hist[t];
        hist[t] = excl;
        int node = b * 256 + t;
        if (node < N_NODES) {
            rowStart[node] = s + excl;
            rowEnd[node]   = s + scan[t];
        }
    }
    __syncthreads();
    for (int j = t; j < len; j += 1024) {
        uint32 kv = keys[j];
        int r = atomicAdd(&hist[kv >> 16], 1);   // LDS atomic
        pairs[s + r] = (kv & 0xFFFFu) | ((uint32)ws[j] << 16);
    }
}

// ---------------- MFMA GEMM (gemm2): C[M,64] = A[M,128] * W[128,64] ----------
template<int NT, bool ABF16, bool OUTFP8>
__global__ __launch_bounds__(256) void mfma_gemm_kernel(const void* __restrict__ Aptr,
                                                        const ushort16* __restrict__ Wt,
                                                        void* __restrict__ Cout, int M) {
    constexpr int N = NT * 16;
    __shared__ ushort16 As[64][136];
    __shared__ ushort16 Ws[N][136];

    const int tid  = threadIdx.x;
    const int wave = tid >> 6;
    const int lane = tid & 63;
    const int quad = lane >> 4;
    const int m    = lane & 15;
    const int blockRow = blockIdx.x * 64;

#pragma unroll
    for (int p = 0; p < N * 16 / 256; p++) {
        int u = tid + 256 * p;
        int row = u / 16, c8 = u % 16;
        uint4 v = ((const uint4*)Wt)[u];
        *((uint4*)&Ws[row][c8 * 8]) = v;
    }
    if (ABF16) {
#pragma unroll
        for (int p = 0; p < 4; p++) {
            int u = tid + 256 * p;
            int row = u / 16, c8 = u % 16;
            int gr = blockRow + row; if (gr > M - 1) gr = M - 1;
            uint4 v = ((const uint4*)Aptr)[gr * 16 + c8];
            *((uint4*)&As[row][c8 * 8]) = v;
        }
    } else {
#pragma unroll
        for (int p = 0; p < 8; p++) {
            int u = tid + 256 * p;
            int row = u / 32, c4 = u % 32;
            int gr = blockRow + row; if (gr > M - 1) gr = M - 1;
            float4 v = ((const float4*)Aptr)[gr * 32 + c4];
            ushort4 s;
            s.x = f2bf(v.x); s.y = f2bf(v.y); s.z = f2bf(v.z); s.w = f2bf(v.w);
            *((ushort4*)&As[row][c4 * 4]) = s;
        }
    }
    __syncthreads();

    f32x4 acc[NT];
#pragma unroll
    for (int nt = 0; nt < NT; nt++) acc[nt] = (f32x4){0.f, 0.f, 0.f, 0.f};

#pragma unroll
    for (int kc = 0; kc < 128; kc += 32) {
        short8 a = *((const short8*)&As[wave * 16 + m][kc + quad * 8]);
#pragma unroll
        for (int nt = 0; nt < NT; nt++) {
            short8 b = *((const short8*)&Ws[nt * 16 + m][kc + quad * 8]);
            acc[nt] = __builtin_amdgcn_mfma_f32_16x16x32_bf16(a, b, acc[nt], 0, 0, 0);
        }
    }

    __syncthreads();
    if (OUTFP8) {
        uchar8* c8lds = (uchar8*)&As[0][0];
#pragma unroll
        for (int nt = 0; nt < NT; nt++)
#pragma unroll
            for (int r = 0; r < 4; r++)
                c8lds[(wave * 16 + quad * 4 + r) * N + nt * 16 + m] = f2fp8(acc[nt][r]);
        __syncthreads();
#pragma unroll
        for (int p = 0; p < 64 * N / 16 / 256; p++) {
            int u = tid + 256 * p;
            int row = u / (N / 16), c16 = u % (N / 16);
            int gr = blockRow + row;
            if (gr < M)
                ((uint4*)Cout)[gr * (N / 16) + c16] = *((const uint4*)&c8lds[row * N + c16 * 16]);
        }
    } else {
#pragma unroll
        for (int nt = 0; nt < NT; nt++)
#pragma unroll
            for (int r = 0; r < 4; r++)
                As[wave * 16 + quad * 4 + r][nt * 16 + m] = f2bf(acc[nt][r]);
        __syncthreads();
#pragma unroll
        for (int p = 0; p < 64 * N / 8 / 256; p++) {
            int u = tid + 256 * p;
            int row = u / (N / 8), c8 = u % (N / 8);
            int gr = blockRow + row;
            if (gr < M)
                ((uint4*)Cout)[gr * (N / 8) + c8] = *((const uint4*)&As[row][c8 * 8]);
        }
    }
}

// ---- agg1: wave = node, 8 edges in flight (octs), 16B/lane gather -----------
// oct = lane>>3 owns edge slots i%8==oct; 8 lanes x uint4 cover the 128B row.
// x2 unroll -> 16 gathers outstanding per wave. 3-stage butterfly combines.
__global__ __launch_bounds__(256) void agg1_kernel(const uint4* __restrict__ H1,
                                                   const int* __restrict__ rowStart,
                                                   const int* __restrict__ rowEnd,
                                                   const uint32* __restrict__ pairs,
                                                   const float* __restrict__ b1,
                                                   uint4* __restrict__ A1) {
    int node = blockIdx.x * 4 + (threadIdx.x >> 6);
    int lane = threadIdx.x & 63;
    int oct = lane >> 3, cl = lane & 7;
    if (node >= N_NODES) return;
    int s = rowStart[node], e = rowEnd[node];
    f32x4 aA = (f32x4){0.f,0.f,0.f,0.f}, aB = aA, aC = aA, aD = aA;
    int i = s + oct;
    for (; i + 8 < e; i += 16) {         // 2 edges per oct, 16 per wave
        uint32 p0 = pairs[i], p1 = pairs[i + 8];
        uint4 h0 = H1[(p0 & 0xFFFFu) * 8 + cl];
        uint4 h1 = H1[(p1 & 0xFFFFu) * 8 + cl];
        float w0 = h_bits2f(p0 >> 16), w1 = h_bits2f(p1 >> 16);
        fp8x4_wacc(h0.x, w0, aA); fp8x4_wacc(h0.y, w0, aB);
        fp8x4_wacc(h0.z, w0, aC); fp8x4_wacc(h0.w, w0, aD);
        fp8x4_wacc(h1.x, w1, aA); fp8x4_wacc(h1.y, w1, aB);
        fp8x4_wacc(h1.z, w1, aC); fp8x4_wacc(h1.w, w1, aD);
    }
    for (; i < e; i += 8) {
        uint32 p = pairs[i];
        uint4 h = H1[(p & 0xFFFFu) * 8 + cl];
        float w = h_bits2f(p >> 16);
        fp8x4_wacc(h.x, w, aA); fp8x4_wacc(h.y, w, aB);
        fp8x4_wacc(h.z, w, aC); fp8x4_wacc(h.w, w, aD);
    }
#pragma unroll
    for (int d = 8; d <= 32; d <<= 1) {
        bfly4(aA, d); bfly4(aB, d); bfly4(aC, d); bfly4(aD, d);
    }
    if (oct == 0) {
        const float4* b1f = (const float4*)b1;
        float4 b0 = b1f[cl * 4], b4 = b1f[cl * 4 + 1], b8 = b1f[cl * 4 + 2], bc = b1f[cl * 4 + 3];
        uint4 r0, r1;
        r0.x = packbf(fmaxf(aA.x + b0.x, 0.f), fmaxf(aA.y + b0.y, 0.f));
        r0.y = packbf(fmaxf(aA.z + b0.z, 0.f), fmaxf(aA.w + b0.w, 0.f));
        r0.z = packbf(fmaxf(aB.x + b4.x, 0.f), fmaxf(aB.y + b4.y, 0.f));
        r0.w = packbf(fmaxf(aB.z + b4.z, 0.f), fmaxf(aB.w + b4.w, 0.f));
        r1.x = packbf(fmaxf(aC.x + b8.x, 0.f), fmaxf(aC.y + b8.y, 0.f));
        r1.y = packbf(fmaxf(aC.z + b8.z, 0.f), fmaxf(aC.w + b8.w, 0.f));
        r1.z = packbf(fmaxf(aD.x + bc.x, 0.f), fmaxf(aD.y + bc.y, 0.f));
        r1.w = packbf(fmaxf(aD.z + bc.z, 0.f), fmaxf(aD.w + bc.w, 0.f));
        A1[node * 16 + cl * 2]     = r0;
        A1[node * 16 + cl * 2 + 1] = r1;
    }
}

// ---- agg2: wave = node, 8 edges in flight (octs), 8B/lane gather ------------
// 8 lanes x uint2 cover the 64B H2 row (8 fp8 channels per lane).
__global__ __launch_bounds__(256) void agg2_kernel(const uint2* __restrict__ H2,
                                                   const int* __restrict__ rowStart,
                                                   const int* __restrict__ rowEnd,
                                                   const uint32* __restrict__ pairs,
                                                   const float* __restrict__ b2,
                                                   float4* __restrict__ out) {
    int node = blockIdx.x * 4 + (threadIdx.x >> 6);
    int lane = threadIdx.x & 63;
    int oct = lane >> 3, cl = lane & 7;
    if (node >= N_NODES) return;
    int s = rowStart[node], e = rowEnd[node];
    f32x4 aX = (f32x4){0.f,0.f,0.f,0.f}, aY = aX;
    int i = s + oct;
    for (; i + 8 < e; i += 16) {         // 2 edges per oct, 16 per wave
        uint32 p0 = pairs[i], p1 = pairs[i + 8];
        uint2 v0 = H2[(p0 & 0xFFFFu) * 8 + cl];
        uint2 v1 = H2[(p1 & 0xFFFFu) * 8 + cl];
        fp8x4_acc(v0.x, aX); fp8x4_acc(v0.y, aY);
        fp8x4_acc(v1.x, aX); fp8x4_acc(v1.y, aY);
    }
    for (; i < e; i += 8) {
        uint2 v = H2[(pairs[i] & 0xFFFFu) * 8 + cl];
        fp8x4_acc(v.x, aX); fp8x4_acc(v.y, aY);
    }
#pragma unroll
    for (int d = 8; d <= 32; d <<= 1) { bfly4(aX, d); bfly4(aY, d); }
    if (oct == 0) {
        const float4* b2f = (const float4*)b2;
        float4 bx = b2f[cl * 2], by = b2f[cl * 2 + 1];
        float4 rx, ry;
        rx.x = aX.x + bx.x; rx.y = aX.y + bx.y; rx.z = aX.z + bx.z; rx.w = aX.w + bx.w;
        ry.x = aY.x + by.x; ry.y = aY.y + by.y; ry.z = aY.z + by.z; ry.w = aY.w + by.w;
        out[node * 16 + cl * 2]     = rx;
        out[node * 16 + cl * 2 + 1] = ry;
    }
}

// ---------------- launch -----------------------------------------------------
extern "C" void kernel_launch(void* const* d_in, const int* in_sizes, int n_in,
                              void* d_out, int out_size, void* d_ws, size_t ws_size,
                              hipStream_t stream) {
    const float* x  = (const float*)d_in[0];
    const int*   ei = (const int*)  d_in[1];   // [2, E] int32
    const float* ew = (const float*)d_in[2];
    const float* W1 = (const float*)d_in[3];
    const float* b1 = (const float*)d_in[4];
    const float* W2 = (const float*)d_in[5];
    const float* b2 = (const float*)d_in[6];
    float* out = (float*)d_out;

    // workspace layout (u32 units)
    uint32* H1      = (uint32*)d_ws;                   // 50000*32  (fp8 [N][128])
    uint32* A1      = H1 + (size_t)N_NODES * 32;       // 50000*64  (bf16 [N][128])
    uint32* H2      = A1 + (size_t)N_NODES * 64;       // 50000*16  (fp8 [N][64])
    uint32* pairs   = H2 + (size_t)N_NODES * 16;       // NBUCKET*CAP (src u16 | f16 w)
    u64* ebuf       = (u64*)(pairs + (size_t)NBUCKET * CAP);  // NBUCKET*CAP u64 staged
    ushort16* W1t   = (ushort16*)(ebuf + (size_t)NBUCKET * CAP);
    ushort16* W2t   = W1t + 128 * 128;                 // 64*128 bf16 transposed
    int* cursorC    = (int*)(W2t + 64 * 128);          // NBUCKET
    int* rowStart   = cursorC + ((NBUCKET + 1) & ~1);  // 50000
    int* rowEnd     = rowStart + N_NODES;              // 50000

    const int nodeBlocks = (N_NODES + 3) / 4;       // 12500

    // W transposes (bf16) + zero coarse cursors
    prep_w_kernel<<<96, 256, 0, stream>>>(W1, W2, W1t, W2t, cursorC);

    // fused: coarse scatter (blocks 0..195) || H1(fp8) = x @ W1 (blocks 196..977)
    gemm1_scatter_kernel<<<SC_BLOCKS + G1_BLOCKS, 256, 0, stream>>>(
        x, W1t, (uchar8*)H1, ei, ew, cursorC, ebuf);

    // fine sort to node granularity within each bucket region
    csr_fine_kernel<<<NBUCKET, 1024, 0, stream>>>(ebuf, cursorC, rowStart, rowEnd, pairs);

    // A1(bf16) = relu(segment_sum(w * H1fp8[src]) + b1)   [wave-per-node, 8 in flight]
    agg1_kernel<<<nodeBlocks, 256, 0, stream>>>((const uint4*)H1, rowStart, rowEnd, pairs, b1, (uint4*)A1);

    // H2(fp8) = A1 @ W2   [MFMA, bf16 A, fp8 out]
    mfma_gemm_kernel<4, true, true><<<G1_BLOCKS, 256, 0, stream>>>(A1, W2t, H2, N_NODES);

    // out = segment_sum(H2[src]) + b2   [wave-per-node, 8 in flight]
    agg2_kernel<<<nodeBlocks, 256, 0, stream>>>((const uint2*)H2, rowStart, rowEnd, pairs, b2, (float4*)out);
}